// Round 7
// baseline (63.826 us; speedup 1.0000x reference)
//
#include <hip/hip_runtime.h>
#include <hip/hip_fp16.h>

typedef _Float16 f16x8 __attribute__((ext_vector_type(8)));
typedef _Float16 f16x4 __attribute__((ext_vector_type(4)));
typedef float f32x4 __attribute__((ext_vector_type(4)));

// ---------------------------------------------------------------------------
// prep_weights: 128 blocks x 256 threads
//   WcT  f16 [128][256]: row o<64 = W_s col o; row 64+o = mean_m W_lin col o
//   Wt16 f16 [64][256] : W_t transposed
//   bmean f32 [64]     : mean_m b_lin
// ---------------------------------------------------------------------------
__global__ void prep_weights(const float* __restrict__ W_lin, const float* __restrict__ b_lin,
                             const float* __restrict__ W_s, const float* __restrict__ W_t,
                             _Float16* __restrict__ WcT, _Float16* __restrict__ Wt16,
                             float* __restrict__ bmean) {
    int tid = blockIdx.x * 256 + threadIdx.x;    // 32768 threads
    if (tid < 16384) {
        int c = tid >> 6, o = tid & 63;
        WcT[o * 256 + c]  = (_Float16)W_s[c * 64 + o];
        Wt16[o * 256 + c] = (_Float16)W_t[c * 64 + o];
    } else {
        int t = tid - 16384;
        int c = t >> 6, o = t & 63;
        float s = 0.f;
        #pragma unroll 8
        for (int m = 0; m < 64; ++m) s += W_lin[m * 16384 + c * 64 + o];
        WcT[(64 + o) * 256 + c] = (_Float16)(s * (1.f / 64.f));
    }
    if (tid < 64) {
        float s = 0.f;
        #pragma unroll 8
        for (int m = 0; m < 64; ++m) s += b_lin[m * 64 + tid];
        bmean[tid] = s * (1.f / 64.f);
    }
}

// ---------------------------------------------------------------------------
// gemm_prep: 768 blocks x 256 threads (4 waves), NO LDS, NO BARRIER.
// B fragments read directly from L2 (WcT/Wt16 are 96 KB total, hot).
//  blocks 0..511 (src), 32 rows each: wave w -> rows (w>>1)*16, col-half w&1.
//     half 0: Ppe[row][o]    = exp((source@W_s)[row][o])           f16
//     half 1: Ppe[row][64+o] = (source@W_mean)[row][o] + bmean[o]  f16
//  blocks 512..767 (tgt), 64 rows each: wave w -> rows w*16, all 64 cols.
//     Et[row][o] = exp((target@W_t)[row][o] + b_s[o] + b_t[o])     f32
// A rows read f32 (full K upfront, 16 loads in flight), cvt f16 in-reg.
// ---------------------------------------------------------------------------
__device__ __forceinline__ f16x8 cvt8(const float* p) {
    f32x4 x = *(const f32x4*)p;
    f32x4 y = *(const f32x4*)(p + 4);
    f16x8 h;
    h[0] = (_Float16)x[0]; h[1] = (_Float16)x[1]; h[2] = (_Float16)x[2]; h[3] = (_Float16)x[3];
    h[4] = (_Float16)y[0]; h[5] = (_Float16)y[1]; h[6] = (_Float16)y[2]; h[7] = (_Float16)y[3];
    return h;
}

__global__ __launch_bounds__(256, 4)
void gemm_prep(const float* __restrict__ source, const float* __restrict__ target,
               const _Float16* __restrict__ WcT, const _Float16* __restrict__ Wt16,
               const float* __restrict__ bmean, const float* __restrict__ b_s,
               const float* __restrict__ b_t,
               _Float16* __restrict__ Ppe, float* __restrict__ Et) {
    const int tid = threadIdx.x;
    const int w = tid >> 6, l = tid & 63;
    const int l15 = l & 15, lq = l >> 4;
    const int b = blockIdx.x;

    if (b < 512) {
        // ---------------- SRC path: 32 rows; wave: 16 rows x 64 cols --------
        const int h  = w & 1;                        // col half: 0=Pe, 1=Pp
        const int rb = b * 32 + (w >> 1) * 16;
        const float* arow = source + (size_t)(rb + l15) * 256;
        f16x8 af[8];
        #pragma unroll
        for (int s = 0; s < 8; ++s) af[s] = cvt8(arow + s * 32 + lq * 8);

        const _Float16* bp = WcT + (size_t)(h * 64 + l15) * 256 + lq * 8;
        f32x4 acc[4] = {};
        #pragma unroll
        for (int s = 0; s < 8; ++s) {
            #pragma unroll
            for (int nt = 0; nt < 4; ++nt) {
                f16x8 bf = *(const f16x8*)(bp + nt * 16 * 256 + s * 32);
                acc[nt] = __builtin_amdgcn_mfma_f32_16x16x32_f16(af[s], bf, acc[nt], 0, 0, 0);
            }
        }

        float bmv[4];
        #pragma unroll
        for (int nt = 0; nt < 4; ++nt) bmv[nt] = h ? bmean[nt * 16 + l15] : 0.f;

        #pragma unroll
        for (int j = 0; j < 4; ++j) {
            int row = rb + lq * 4 + j;
            #pragma unroll
            for (int nt = 0; nt < 4; ++nt) {
                float v = acc[nt][j];
                _Float16 r = h ? (_Float16)(v + bmv[nt]) : (_Float16)__expf(v);
                Ppe[row * 128 + h * 64 + nt * 16 + l15] = r;
            }
        }
    } else {
        // ---------------- TGT path: 64 rows; wave: 16 rows x 64 cols --------
        const int rb = (b - 512) * 64 + w * 16;
        const float* arow = target + (size_t)(rb + l15) * 256;
        f16x8 af[8];
        #pragma unroll
        for (int s = 0; s < 8; ++s) af[s] = cvt8(arow + s * 32 + lq * 8);

        const _Float16* bp = Wt16 + (size_t)l15 * 256 + lq * 8;
        f32x4 acc[4] = {};
        #pragma unroll
        for (int s = 0; s < 8; ++s) {
            #pragma unroll
            for (int nt = 0; nt < 4; ++nt) {
                f16x8 bf = *(const f16x8*)(bp + nt * 16 * 256 + s * 32);
                acc[nt] = __builtin_amdgcn_mfma_f32_16x16x32_f16(af[s], bf, acc[nt], 0, 0, 0);
            }
        }

        float bsv[4];
        #pragma unroll
        for (int nt = 0; nt < 4; ++nt) {
            int col = nt * 16 + l15;
            bsv[nt] = b_s[col] + b_t[col];
        }
        #pragma unroll
        for (int j = 0; j < 4; ++j) {
            int row = rb + lq * 4 + j;
            #pragma unroll
            for (int nt = 0; nt < 4; ++nt)
                Et[row * 64 + nt * 16 + l15] = __expf(acc[nt][j] + bsv[nt]);
        }
    }
}

// ---------------------------------------------------------------------------
// epilogue: 2048 blocks x 256 threads; TWO target nodes per wave (64 rows).
// All index loads + gathers issued up front (32 gather pairs in flight per
// lane) to maximize memory-level parallelism; normal (cached) stores.
// Lane (lq,l15): group g handles 4 rows (lq) x 4 cols (l15*4..+3).
// out[r][o] = Pe[nb][o]*Et[n][o] / sum_o(Pe*Et) * Pp[nb][o]
// ---------------------------------------------------------------------------
__global__ __launch_bounds__(256)
void epilogue(const int* __restrict__ neighbors, const _Float16* __restrict__ Ppe,
              const float* __restrict__ Et, float* __restrict__ out) {
    const int tid = threadIdx.x;
    const int w = tid >> 6, l = tid & 63;
    const int lq = l >> 4, l15 = l & 15;
    const int n0 = blockIdx.x * 8 + w * 2;      // this wave: n0, n0+1
    const int co = l15 * 4;

    f32x4 et0 = *(const f32x4*)(Et + n0 * 64 + co);
    f32x4 et1 = *(const f32x4*)(Et + (n0 + 1) * 64 + co);

    int nb0[8], nb1[8];
    #pragma unroll
    for (int g = 0; g < 8; ++g) nb0[g] = neighbors[n0 * 32 + g * 4 + lq];
    #pragma unroll
    for (int g = 0; g < 8; ++g) nb1[g] = neighbors[(n0 + 1) * 32 + g * 4 + lq];

    f16x4 pe0[8], pp0[8], pe1[8], pp1[8];
    #pragma unroll
    for (int g = 0; g < 8; ++g) {
        pe0[g] = *(const f16x4*)(Ppe + nb0[g] * 128 + co);
        pp0[g] = *(const f16x4*)(Ppe + nb0[g] * 128 + 64 + co);
    }
    #pragma unroll
    for (int g = 0; g < 8; ++g) {
        pe1[g] = *(const f16x4*)(Ppe + nb1[g] * 128 + co);
        pp1[g] = *(const f16x4*)(Ppe + nb1[g] * 128 + 64 + co);
    }

    #pragma unroll
    for (int g = 0; g < 8; ++g) {
        float w0 = (float)pe0[g][0] * et0[0];
        float w1 = (float)pe0[g][1] * et0[1];
        float w2 = (float)pe0[g][2] * et0[2];
        float w3 = (float)pe0[g][3] * et0[3];
        float s = (w0 + w1) + (w2 + w3);
        s += __shfl_xor(s, 1);
        s += __shfl_xor(s, 2);
        s += __shfl_xor(s, 4);
        s += __shfl_xor(s, 8);
        float inv = 1.0f / s;
        f32x4 o;
        o[0] = w0 * inv * (float)pp0[g][0];
        o[1] = w1 * inv * (float)pp0[g][1];
        o[2] = w2 * inv * (float)pp0[g][2];
        o[3] = w3 * inv * (float)pp0[g][3];
        *(f32x4*)(out + (size_t)(n0 * 32 + g * 4 + lq) * 64 + co) = o;
    }
    #pragma unroll
    for (int g = 0; g < 8; ++g) {
        float w0 = (float)pe1[g][0] * et1[0];
        float w1 = (float)pe1[g][1] * et1[1];
        float w2 = (float)pe1[g][2] * et1[2];
        float w3 = (float)pe1[g][3] * et1[3];
        float s = (w0 + w1) + (w2 + w3);
        s += __shfl_xor(s, 1);
        s += __shfl_xor(s, 2);
        s += __shfl_xor(s, 4);
        s += __shfl_xor(s, 8);
        float inv = 1.0f / s;
        f32x4 o;
        o[0] = w0 * inv * (float)pp1[g][0];
        o[1] = w1 * inv * (float)pp1[g][1];
        o[2] = w2 * inv * (float)pp1[g][2];
        o[3] = w3 * inv * (float)pp1[g][3];
        *(f32x4*)(out + (size_t)((n0 + 1) * 32 + g * 4 + lq) * 64 + co) = o;
    }
}

// ---------------------------------------------------------------------------
extern "C" void kernel_launch(void* const* d_in, const int* in_sizes, int n_in,
                              void* d_out, int out_size, void* d_ws, size_t ws_size,
                              hipStream_t stream) {
    const float* source    = (const float*)d_in[0];
    const float* target    = (const float*)d_in[1];
    const int*   neighbors = (const int*)d_in[2];
    const float* W_lin     = (const float*)d_in[3];
    const float* b_lin     = (const float*)d_in[4];
    const float* W_s       = (const float*)d_in[5];
    const float* b_s       = (const float*)d_in[6];
    const float* W_t       = (const float*)d_in[7];
    const float* b_t       = (const float*)d_in[8];

    char* ws = (char*)d_ws;
    _Float16* Ppe   = (_Float16*)ws;                          // 4 MiB
    float*    Et    = (float*)(ws + (4u << 20));              // 4 MiB
    _Float16* WcT   = (_Float16*)(ws + (8u << 20));           // 64 KiB
    _Float16* Wt16  = (_Float16*)(ws + (8u << 20) + 65536);   // 32 KiB
    float*    bmean = (float*)(ws + (8u << 20) + 98304);      // 256 B
    float*    out   = (float*)d_out;

    prep_weights<<<128, 256, 0, stream>>>(W_lin, b_lin, W_s, W_t, WcT, Wt16, bmean);
    gemm_prep<<<768, 256, 0, stream>>>(source, target, WcT, Wt16, bmean, b_s, b_t,
                                       Ppe, Et);
    epilogue<<<2048, 256, 0, stream>>>(neighbors, Ppe, Et, out);
}

// Round 8
// 53.136 us; speedup vs baseline: 1.2012x; 1.2012x over previous
//
#include <hip/hip_runtime.h>
#include <hip/hip_fp16.h>

typedef _Float16 f16x8 __attribute__((ext_vector_type(8)));
typedef _Float16 f16x4 __attribute__((ext_vector_type(4)));
typedef float f32x4 __attribute__((ext_vector_type(4)));

// ---------------------------------------------------------------------------
// prep_weights: 128 blocks x 256 threads
//   WcT  f16 [128][256]: row o<64 = W_s col o; row 64+o = mean_m W_lin col o
//   Wt16 f16 [64][256] : W_t transposed
//   bmean f32 [64]     : mean_m b_lin
// ---------------------------------------------------------------------------
__global__ void prep_weights(const float* __restrict__ W_lin, const float* __restrict__ b_lin,
                             const float* __restrict__ W_s, const float* __restrict__ W_t,
                             _Float16* __restrict__ WcT, _Float16* __restrict__ Wt16,
                             float* __restrict__ bmean) {
    int tid = blockIdx.x * 256 + threadIdx.x;    // 32768 threads
    if (tid < 16384) {
        int c = tid >> 6, o = tid & 63;
        WcT[o * 256 + c]  = (_Float16)W_s[c * 64 + o];
        Wt16[o * 256 + c] = (_Float16)W_t[c * 64 + o];
    } else {
        int t = tid - 16384;
        int c = t >> 6, o = t & 63;
        float s = 0.f;
        #pragma unroll 8
        for (int m = 0; m < 64; ++m) s += W_lin[m * 16384 + c * 64 + o];
        WcT[(64 + o) * 256 + c] = (_Float16)(s * (1.f / 64.f));
    }
    if (tid < 64) {
        float s = 0.f;
        #pragma unroll 8
        for (int m = 0; m < 64; ++m) s += b_lin[m * 64 + tid];
        bmean[tid] = s * (1.f / 64.f);
    }
}

// ---------------------------------------------------------------------------
// gemm_prep: 512 blocks x 256 threads (4 waves), 64 A-rows per block.
// B staged fragment-major in LDS (conflict-free ds_read_b128 at l*16+imm);
// one barrier; A rows read f32 upfront (16 loads in flight), cvt f16 in-reg.
//  blocks 0..255  (src): Ppe row = per-4-col-group interleaved [pe(4)|pp(4)]:
//     col c: pe at (c>>2)*8+(c&3), pp at (c>>2)*8+4+(c&3)
//     pe = exp((source@W_s)[r][c]);  pp = (source@W_mean)[r][c] + bmean[c]
//  blocks 256..511 (tgt): Et[r][o] = exp((target@W_t)[r][o]+b_s[o]+b_t[o]) f32
// ---------------------------------------------------------------------------
__device__ __forceinline__ f16x8 cvt8(const float* p) {
    f32x4 x = *(const f32x4*)p;
    f32x4 y = *(const f32x4*)(p + 4);
    f16x8 h;
    h[0] = (_Float16)x[0]; h[1] = (_Float16)x[1]; h[2] = (_Float16)x[2]; h[3] = (_Float16)x[3];
    h[4] = (_Float16)y[0]; h[5] = (_Float16)y[1]; h[6] = (_Float16)y[2]; h[7] = (_Float16)y[3];
    return h;
}

__global__ __launch_bounds__(256, 2)
void gemm_prep(const float* __restrict__ source, const float* __restrict__ target,
               const _Float16* __restrict__ WcT, const _Float16* __restrict__ Wt16,
               const float* __restrict__ bmean, const float* __restrict__ b_s,
               const float* __restrict__ b_t,
               _Float16* __restrict__ Ppe, float* __restrict__ Et) {
    __shared__ _Float16 lds[32768];   // SRC path uses 64 KiB, TGT 32 KiB

    const int tid = threadIdx.x;
    const int w = tid >> 6, l = tid & 63;
    const int l15 = l & 15, lq = l >> 4;
    const int b = blockIdx.x;

    if (b < 256) {
        // ---------------- SRC path ----------------
        const int rb = b * 64;
        const float* arow = source + (size_t)(rb + w * 16 + l15) * 256;
        f16x8 af[8];
        #pragma unroll
        for (int s = 0; s < 8; ++s) af[s] = cvt8(arow + s * 32 + lq * 8);

        #pragma unroll
        for (int i = 0; i < 16; ++i) {
            int c = i * 256 + tid;                   // 4096 chunks
            int fi = c >> 6, lane = c & 63;
            int nt = fi >> 3, s = fi & 7;
            f16x8 v = *(const f16x8*)(WcT + (nt * 16 + (lane & 15)) * 256 + s * 32 + (lane >> 4) * 8);
            *(f16x8*)((char*)lds + c * 16) = v;
        }
        __syncthreads();

        const char* bb = (const char*)lds + l * 16;
        f32x4 acc[8] = {};
        #pragma unroll
        for (int s = 0; s < 8; ++s) {
            #pragma unroll
            for (int nt = 0; nt < 8; ++nt) {
                f16x8 bf = *(const f16x8*)(bb + nt * 8192 + s * 1024);
                acc[nt] = __builtin_amdgcn_mfma_f32_16x16x32_f16(af[s], bf, acc[nt], 0, 0, 0);
            }
        }

        float bmv[4];
        #pragma unroll
        for (int nt = 0; nt < 4; ++nt) bmv[nt] = bmean[nt * 16 + l15];
        // interleaved position for col c = nt*16 + l15:
        //   pe: nt*32 + (l15>>2)*8 + (l15&3);  pp: +4
        const int ip = (l15 >> 2) * 8 + (l15 & 3);
        #pragma unroll
        for (int j = 0; j < 4; ++j) {
            int row = rb + w * 16 + lq * 4 + j;
            #pragma unroll
            for (int nt = 0; nt < 4; ++nt) {
                Ppe[row * 128 + nt * 32 + ip]     = (_Float16)__expf(acc[nt][j]);
                Ppe[row * 128 + nt * 32 + ip + 4] = (_Float16)(acc[nt + 4][j] + bmv[nt]);
            }
        }
    } else {
        // ---------------- TGT path ----------------
        const int rb = (b - 256) * 64;
        const float* arow = target + (size_t)(rb + w * 16 + l15) * 256;
        f16x8 af[8];
        #pragma unroll
        for (int s = 0; s < 8; ++s) af[s] = cvt8(arow + s * 32 + lq * 8);

        #pragma unroll
        for (int i = 0; i < 8; ++i) {
            int c = i * 256 + tid;                   // 2048 chunks
            int fi = c >> 6, lane = c & 63;
            int nt = fi >> 3, s = fi & 7;
            f16x8 v = *(const f16x8*)(Wt16 + (nt * 16 + (lane & 15)) * 256 + s * 32 + (lane >> 4) * 8);
            *(f16x8*)((char*)lds + c * 16) = v;
        }
        __syncthreads();

        const char* bb = (const char*)lds + l * 16;
        f32x4 acc[4] = {};
        #pragma unroll
        for (int s = 0; s < 8; ++s) {
            #pragma unroll
            for (int nt = 0; nt < 4; ++nt) {
                f16x8 bf = *(const f16x8*)(bb + nt * 8192 + s * 1024);
                acc[nt] = __builtin_amdgcn_mfma_f32_16x16x32_f16(af[s], bf, acc[nt], 0, 0, 0);
            }
        }

        float bsv[4];
        #pragma unroll
        for (int nt = 0; nt < 4; ++nt) {
            int col = nt * 16 + l15;
            bsv[nt] = b_s[col] + b_t[col];
        }
        #pragma unroll
        for (int j = 0; j < 4; ++j) {
            int row = rb + w * 16 + lq * 4 + j;
            #pragma unroll
            for (int nt = 0; nt < 4; ++nt)
                Et[row * 64 + nt * 16 + l15] = __expf(acc[nt][j] + bsv[nt]);
        }
    }
}

// ---------------------------------------------------------------------------
// epilogue: 2048 blocks x 256 threads; TWO target nodes per wave (64 rows).
// One f16x8 gather per neighbor per lane (interleaved [pe4|pp4] layout):
// 8 loads/node/lane, all issued up front. Lane (lq,l15): group g handles
// 4 rows (lq) x 4 cols (l15*4..+3).
// out[r][o] = pe[nb][o]*Et[n][o] / sum_o(pe*Et) * pp[nb][o]
// ---------------------------------------------------------------------------
__global__ __launch_bounds__(256)
void epilogue(const int* __restrict__ neighbors, const _Float16* __restrict__ Ppe,
              const float* __restrict__ Et, float* __restrict__ out) {
    const int tid = threadIdx.x;
    const int w = tid >> 6, l = tid & 63;
    const int lq = l >> 4, l15 = l & 15;
    const int n0 = blockIdx.x * 8 + w * 2;      // this wave: n0, n0+1
    const int co = l15 * 4;
    const int ro = l15 * 8;                     // byte-pair offset of col-group

    f32x4 et0 = *(const f32x4*)(Et + n0 * 64 + co);
    f32x4 et1 = *(const f32x4*)(Et + (n0 + 1) * 64 + co);

    int nb0[8], nb1[8];
    #pragma unroll
    for (int g = 0; g < 8; ++g) nb0[g] = neighbors[n0 * 32 + g * 4 + lq];
    #pragma unroll
    for (int g = 0; g < 8; ++g) nb1[g] = neighbors[(n0 + 1) * 32 + g * 4 + lq];

    f16x8 q0[8], q1[8];
    #pragma unroll
    for (int g = 0; g < 8; ++g) q0[g] = *(const f16x8*)(Ppe + nb0[g] * 128 + ro);
    #pragma unroll
    for (int g = 0; g < 8; ++g) q1[g] = *(const f16x8*)(Ppe + nb1[g] * 128 + ro);

    #pragma unroll
    for (int g = 0; g < 8; ++g) {
        float w0 = (float)q0[g][0] * et0[0];
        float w1 = (float)q0[g][1] * et0[1];
        float w2 = (float)q0[g][2] * et0[2];
        float w3 = (float)q0[g][3] * et0[3];
        float s = (w0 + w1) + (w2 + w3);
        s += __shfl_xor(s, 1);
        s += __shfl_xor(s, 2);
        s += __shfl_xor(s, 4);
        s += __shfl_xor(s, 8);
        float inv = 1.0f / s;
        f32x4 o;
        o[0] = w0 * inv * (float)q0[g][4];
        o[1] = w1 * inv * (float)q0[g][5];
        o[2] = w2 * inv * (float)q0[g][6];
        o[3] = w3 * inv * (float)q0[g][7];
        *(f32x4*)(out + (size_t)(n0 * 32 + g * 4 + lq) * 64 + co) = o;
    }
    #pragma unroll
    for (int g = 0; g < 8; ++g) {
        float w0 = (float)q1[g][0] * et1[0];
        float w1 = (float)q1[g][1] * et1[1];
        float w2 = (float)q1[g][2] * et1[2];
        float w3 = (float)q1[g][3] * et1[3];
        float s = (w0 + w1) + (w2 + w3);
        s += __shfl_xor(s, 1);
        s += __shfl_xor(s, 2);
        s += __shfl_xor(s, 4);
        s += __shfl_xor(s, 8);
        float inv = 1.0f / s;
        f32x4 o;
        o[0] = w0 * inv * (float)q1[g][4];
        o[1] = w1 * inv * (float)q1[g][5];
        o[2] = w2 * inv * (float)q1[g][6];
        o[3] = w3 * inv * (float)q1[g][7];
        *(f32x4*)(out + (size_t)((n0 + 1) * 32 + g * 4 + lq) * 64 + co) = o;
    }
}

// ---------------------------------------------------------------------------
extern "C" void kernel_launch(void* const* d_in, const int* in_sizes, int n_in,
                              void* d_out, int out_size, void* d_ws, size_t ws_size,
                              hipStream_t stream) {
    const float* source    = (const float*)d_in[0];
    const float* target    = (const float*)d_in[1];
    const int*   neighbors = (const int*)d_in[2];
    const float* W_lin     = (const float*)d_in[3];
    const float* b_lin     = (const float*)d_in[4];
    const float* W_s       = (const float*)d_in[5];
    const float* b_s       = (const float*)d_in[6];
    const float* W_t       = (const float*)d_in[7];
    const float* b_t       = (const float*)d_in[8];

    char* ws = (char*)d_ws;
    _Float16* Ppe   = (_Float16*)ws;                          // 4 MiB
    float*    Et    = (float*)(ws + (4u << 20));              // 4 MiB
    _Float16* WcT   = (_Float16*)(ws + (8u << 20));           // 64 KiB
    _Float16* Wt16  = (_Float16*)(ws + (8u << 20) + 65536);   // 32 KiB
    float*    bmean = (float*)(ws + (8u << 20) + 98304);      // 256 B
    float*    out   = (float*)d_out;

    prep_weights<<<128, 256, 0, stream>>>(W_lin, b_lin, W_s, W_t, WcT, Wt16, bmean);
    gemm_prep<<<512, 256, 0, stream>>>(source, target, WcT, Wt16, bmean, b_s, b_t,
                                       Ppe, Et);
    epilogue<<<2048, 256, 0, stream>>>(neighbors, Ppe, Et, out);
}

// Round 9
// 53.014 us; speedup vs baseline: 1.2039x; 1.0023x over previous
//
#include <hip/hip_runtime.h>
#include <hip/hip_fp16.h>

typedef _Float16 f16x8 __attribute__((ext_vector_type(8)));
typedef _Float16 f16x4 __attribute__((ext_vector_type(4)));
typedef float f32x4 __attribute__((ext_vector_type(4)));
typedef int   i32x4 __attribute__((ext_vector_type(4)));

// ---------------------------------------------------------------------------
// prep_weights: 128 blocks x 256 threads
//   WcT  f16 [128][256]: row o<64 = W_s col o; row 64+o = mean_m W_lin col o
//   Wt16 f16 [64][256] : W_t transposed
//   bmean f32 [64]     : mean_m b_lin
// ---------------------------------------------------------------------------
__global__ void prep_weights(const float* __restrict__ W_lin, const float* __restrict__ b_lin,
                             const float* __restrict__ W_s, const float* __restrict__ W_t,
                             _Float16* __restrict__ WcT, _Float16* __restrict__ Wt16,
                             float* __restrict__ bmean) {
    int tid = blockIdx.x * 256 + threadIdx.x;    // 32768 threads
    if (tid < 16384) {
        int c = tid >> 6, o = tid & 63;
        WcT[o * 256 + c]  = (_Float16)W_s[c * 64 + o];
        Wt16[o * 256 + c] = (_Float16)W_t[c * 64 + o];
    } else {
        int t = tid - 16384;
        int c = t >> 6, o = t & 63;
        float s = 0.f;
        #pragma unroll 8
        for (int m = 0; m < 64; ++m) s += W_lin[m * 16384 + c * 64 + o];
        WcT[(64 + o) * 256 + c] = (_Float16)(s * (1.f / 64.f));
    }
    if (tid < 64) {
        float s = 0.f;
        #pragma unroll 8
        for (int m = 0; m < 64; ++m) s += b_lin[m * 64 + tid];
        bmean[tid] = s * (1.f / 64.f);
    }
}

// ---------------------------------------------------------------------------
// gemm_prep: 512 blocks x 256 threads (4 waves), 64 A-rows per block.
// B staged fragment-major in LDS (conflict-free ds_read_b128 at l*16+imm);
// one barrier; A rows read f32 upfront (16 loads in flight), cvt f16 in-reg.
//  blocks 0..255  (src): Ppe row = per-4-col-group interleaved [pe(4)|pp(4)]:
//     col c: pe at (c>>2)*8+(c&3), pp at (c>>2)*8+4+(c&3)
//     pe = exp((source@W_s)[r][c]);  pp = (source@W_mean)[r][c] + bmean[c]
//  blocks 256..511 (tgt): Et[r][o] = exp((target@W_t)[r][o]+b_s[o]+b_t[o]) f32
// ---------------------------------------------------------------------------
__device__ __forceinline__ f16x8 cvt8(const float* p) {
    f32x4 x = *(const f32x4*)p;
    f32x4 y = *(const f32x4*)(p + 4);
    f16x8 h;
    h[0] = (_Float16)x[0]; h[1] = (_Float16)x[1]; h[2] = (_Float16)x[2]; h[3] = (_Float16)x[3];
    h[4] = (_Float16)y[0]; h[5] = (_Float16)y[1]; h[6] = (_Float16)y[2]; h[7] = (_Float16)y[3];
    return h;
}

__global__ __launch_bounds__(256, 2)
void gemm_prep(const float* __restrict__ source, const float* __restrict__ target,
               const _Float16* __restrict__ WcT, const _Float16* __restrict__ Wt16,
               const float* __restrict__ bmean, const float* __restrict__ b_s,
               const float* __restrict__ b_t,
               _Float16* __restrict__ Ppe, float* __restrict__ Et) {
    __shared__ _Float16 lds[32768];   // SRC path uses 64 KiB, TGT 32 KiB

    const int tid = threadIdx.x;
    const int w = tid >> 6, l = tid & 63;
    const int l15 = l & 15, lq = l >> 4;
    const int b = blockIdx.x;

    if (b < 256) {
        // ---------------- SRC path ----------------
        const int rb = b * 64;
        const float* arow = source + (size_t)(rb + w * 16 + l15) * 256;
        f16x8 af[8];
        #pragma unroll
        for (int s = 0; s < 8; ++s) af[s] = cvt8(arow + s * 32 + lq * 8);

        #pragma unroll
        for (int i = 0; i < 16; ++i) {
            int c = i * 256 + tid;                   // 4096 chunks
            int fi = c >> 6, lane = c & 63;
            int nt = fi >> 3, s = fi & 7;
            f16x8 v = *(const f16x8*)(WcT + (nt * 16 + (lane & 15)) * 256 + s * 32 + (lane >> 4) * 8);
            *(f16x8*)((char*)lds + c * 16) = v;
        }
        __syncthreads();

        const char* bb = (const char*)lds + l * 16;
        f32x4 acc[8] = {};
        #pragma unroll
        for (int s = 0; s < 8; ++s) {
            #pragma unroll
            for (int nt = 0; nt < 8; ++nt) {
                f16x8 bf = *(const f16x8*)(bb + nt * 8192 + s * 1024);
                acc[nt] = __builtin_amdgcn_mfma_f32_16x16x32_f16(af[s], bf, acc[nt], 0, 0, 0);
            }
        }

        float bmv[4];
        #pragma unroll
        for (int nt = 0; nt < 4; ++nt) bmv[nt] = bmean[nt * 16 + l15];
        // interleaved position for col c = nt*16 + l15:
        //   pe: nt*32 + (l15>>2)*8 + (l15&3);  pp: +4
        const int ip = (l15 >> 2) * 8 + (l15 & 3);
        #pragma unroll
        for (int j = 0; j < 4; ++j) {
            int row = rb + w * 16 + lq * 4 + j;
            #pragma unroll
            for (int nt = 0; nt < 4; ++nt) {
                Ppe[row * 128 + nt * 32 + ip]     = (_Float16)__expf(acc[nt][j]);
                Ppe[row * 128 + nt * 32 + ip + 4] = (_Float16)(acc[nt + 4][j] + bmv[nt]);
            }
        }
    } else {
        // ---------------- TGT path ----------------
        const int rb = (b - 256) * 64;
        const float* arow = target + (size_t)(rb + w * 16 + l15) * 256;
        f16x8 af[8];
        #pragma unroll
        for (int s = 0; s < 8; ++s) af[s] = cvt8(arow + s * 32 + lq * 8);

        #pragma unroll
        for (int i = 0; i < 8; ++i) {
            int c = i * 256 + tid;                   // 2048 chunks
            int fi = c >> 6, lane = c & 63;
            int nt = fi >> 3, s = fi & 7;
            f16x8 v = *(const f16x8*)(Wt16 + (nt * 16 + (lane & 15)) * 256 + s * 32 + (lane >> 4) * 8);
            *(f16x8*)((char*)lds + c * 16) = v;
        }
        __syncthreads();

        const char* bb = (const char*)lds + l * 16;
        f32x4 acc[4] = {};
        #pragma unroll
        for (int s = 0; s < 8; ++s) {
            #pragma unroll
            for (int nt = 0; nt < 4; ++nt) {
                f16x8 bf = *(const f16x8*)(bb + nt * 8192 + s * 1024);
                acc[nt] = __builtin_amdgcn_mfma_f32_16x16x32_f16(af[s], bf, acc[nt], 0, 0, 0);
            }
        }

        float bsv[4];
        #pragma unroll
        for (int nt = 0; nt < 4; ++nt) {
            int col = nt * 16 + l15;
            bsv[nt] = b_s[col] + b_t[col];
        }
        #pragma unroll
        for (int j = 0; j < 4; ++j) {
            int row = rb + w * 16 + lq * 4 + j;
            #pragma unroll
            for (int nt = 0; nt < 4; ++nt)
                Et[row * 64 + nt * 16 + l15] = __expf(acc[nt][j] + bsv[nt]);
        }
    }
}

// ---------------------------------------------------------------------------
// epilogue: 2048 blocks x 256 threads; TWO target nodes per wave.
// Row map r = n*32 + lq*8 + g (g=0..7): per-lane CONSECUTIVE neighbor
// indices -> nb loaded as int4 x2 per node. One f16x8 gather per neighbor
// (interleaved [pe4|pp4] layout), all issued up front (compiler sinks under
// the VGPR cap). __launch_bounds__(256,5): VGPR<=102 -> 5 blocks/CU resident.
// Reduce over the 16 l15 lanes (shfl masks <16); 256-B store granules.
// out[r][o] = pe[nb][o]*Et[n][o] / sum_o(pe*Et) * pp[nb][o]
// ---------------------------------------------------------------------------
__global__ __launch_bounds__(256, 5)
void epilogue(const int* __restrict__ neighbors, const _Float16* __restrict__ Ppe,
              const float* __restrict__ Et, float* __restrict__ out) {
    const int tid = threadIdx.x;
    const int w = tid >> 6, l = tid & 63;
    const int lq = l >> 4, l15 = l & 15;
    const int n0 = blockIdx.x * 8 + w * 2;      // this wave: n0, n0+1
    const int co = l15 * 4;
    const int ro = l15 * 8;                     // elem offset of col-group

    i32x4 na0 = *(const i32x4*)(neighbors + n0 * 32 + lq * 8);
    i32x4 na1 = *(const i32x4*)(neighbors + n0 * 32 + lq * 8 + 4);
    i32x4 nc0 = *(const i32x4*)(neighbors + (n0 + 1) * 32 + lq * 8);
    i32x4 nc1 = *(const i32x4*)(neighbors + (n0 + 1) * 32 + lq * 8 + 4);

    f32x4 et0 = *(const f32x4*)(Et + n0 * 64 + co);
    f32x4 et1 = *(const f32x4*)(Et + (n0 + 1) * 64 + co);

    f16x8 q0[8], q1[8];
    #pragma unroll
    for (int g = 0; g < 4; ++g) q0[g]     = *(const f16x8*)(Ppe + na0[g] * 128 + ro);
    #pragma unroll
    for (int g = 0; g < 4; ++g) q0[4 + g] = *(const f16x8*)(Ppe + na1[g] * 128 + ro);
    #pragma unroll
    for (int g = 0; g < 4; ++g) q1[g]     = *(const f16x8*)(Ppe + nc0[g] * 128 + ro);
    #pragma unroll
    for (int g = 0; g < 4; ++g) q1[4 + g] = *(const f16x8*)(Ppe + nc1[g] * 128 + ro);

    #pragma unroll
    for (int g = 0; g < 8; ++g) {
        float w0 = (float)q0[g][0] * et0[0];
        float w1 = (float)q0[g][1] * et0[1];
        float w2 = (float)q0[g][2] * et0[2];
        float w3 = (float)q0[g][3] * et0[3];
        float s = (w0 + w1) + (w2 + w3);
        s += __shfl_xor(s, 1);
        s += __shfl_xor(s, 2);
        s += __shfl_xor(s, 4);
        s += __shfl_xor(s, 8);
        float inv = 1.0f / s;
        f32x4 o;
        o[0] = w0 * inv * (float)q0[g][4];
        o[1] = w1 * inv * (float)q0[g][5];
        o[2] = w2 * inv * (float)q0[g][6];
        o[3] = w3 * inv * (float)q0[g][7];
        *(f32x4*)(out + (size_t)(n0 * 32 + lq * 8 + g) * 64 + co) = o;
    }
    #pragma unroll
    for (int g = 0; g < 8; ++g) {
        float w0 = (float)q1[g][0] * et1[0];
        float w1 = (float)q1[g][1] * et1[1];
        float w2 = (float)q1[g][2] * et1[2];
        float w3 = (float)q1[g][3] * et1[3];
        float s = (w0 + w1) + (w2 + w3);
        s += __shfl_xor(s, 1);
        s += __shfl_xor(s, 2);
        s += __shfl_xor(s, 4);
        s += __shfl_xor(s, 8);
        float inv = 1.0f / s;
        f32x4 o;
        o[0] = w0 * inv * (float)q1[g][4];
        o[1] = w1 * inv * (float)q1[g][5];
        o[2] = w2 * inv * (float)q1[g][6];
        o[3] = w3 * inv * (float)q1[g][7];
        *(f32x4*)(out + (size_t)((n0 + 1) * 32 + lq * 8 + g) * 64 + co) = o;
    }
}

// ---------------------------------------------------------------------------
extern "C" void kernel_launch(void* const* d_in, const int* in_sizes, int n_in,
                              void* d_out, int out_size, void* d_ws, size_t ws_size,
                              hipStream_t stream) {
    const float* source    = (const float*)d_in[0];
    const float* target    = (const float*)d_in[1];
    const int*   neighbors = (const int*)d_in[2];
    const float* W_lin     = (const float*)d_in[3];
    const float* b_lin     = (const float*)d_in[4];
    const float* W_s       = (const float*)d_in[5];
    const float* b_s       = (const float*)d_in[6];
    const float* W_t       = (const float*)d_in[7];
    const float* b_t       = (const float*)d_in[8];

    char* ws = (char*)d_ws;
    _Float16* Ppe   = (_Float16*)ws;                          // 4 MiB
    float*    Et    = (float*)(ws + (4u << 20));              // 4 MiB
    _Float16* WcT   = (_Float16*)(ws + (8u << 20));           // 64 KiB
    _Float16* Wt16  = (_Float16*)(ws + (8u << 20) + 65536);   // 32 KiB
    float*    bmean = (float*)(ws + (8u << 20) + 98304);      // 256 B
    float*    out   = (float*)d_out;

    prep_weights<<<128, 256, 0, stream>>>(W_lin, b_lin, W_s, W_t, WcT, Wt16, bmean);
    gemm_prep<<<512, 256, 0, stream>>>(source, target, WcT, Wt16, bmean, b_s, b_t,
                                       Ppe, Et);
    epilogue<<<2048, 256, 0, stream>>>(neighbors, Ppe, Et, out);
}

// Round 10
// 47.779 us; speedup vs baseline: 1.3359x; 1.1096x over previous
//
#include <hip/hip_runtime.h>
#include <hip/hip_fp16.h>

typedef _Float16 f16x8 __attribute__((ext_vector_type(8)));
typedef _Float16 f16x4 __attribute__((ext_vector_type(4)));
typedef float f32x4 __attribute__((ext_vector_type(4)));
typedef int   i32x4 __attribute__((ext_vector_type(4)));

// ---------------------------------------------------------------------------
// prep_weights: 128 blocks x 256 threads
//   WcT  f16 [128][256]: row o<64 = W_s col o; row 64+o = mean_m W_lin col o
//   Wt16 f16 [64][256] : W_t transposed
//   bmean f32 [64]     : mean_m b_lin
// ---------------------------------------------------------------------------
__global__ void prep_weights(const float* __restrict__ W_lin, const float* __restrict__ b_lin,
                             const float* __restrict__ W_s, const float* __restrict__ W_t,
                             _Float16* __restrict__ WcT, _Float16* __restrict__ Wt16,
                             float* __restrict__ bmean) {
    int tid = blockIdx.x * 256 + threadIdx.x;    // 32768 threads
    if (tid < 16384) {
        int c = tid >> 6, o = tid & 63;
        WcT[o * 256 + c]  = (_Float16)W_s[c * 64 + o];
        Wt16[o * 256 + c] = (_Float16)W_t[c * 64 + o];
    } else {
        int t = tid - 16384;
        int c = t >> 6, o = t & 63;
        float s = 0.f;
        #pragma unroll 8
        for (int m = 0; m < 64; ++m) s += W_lin[m * 16384 + c * 64 + o];
        WcT[(64 + o) * 256 + c] = (_Float16)(s * (1.f / 64.f));
    }
    if (tid < 64) {
        float s = 0.f;
        #pragma unroll 8
        for (int m = 0; m < 64; ++m) s += b_lin[m * 64 + tid];
        bmean[tid] = s * (1.f / 64.f);
    }
}

// ---------------------------------------------------------------------------
// gemm_prep: 512 blocks x 256 threads (4 waves), 64 A-rows per block.
// B staged fragment-major in LDS (conflict-free ds_read_b128 at l*16+imm);
// one barrier; A rows read f32 upfront (16 loads in flight), cvt f16 in-reg.
//  blocks 0..255  (src): Ppe row = per-4-col-group interleaved [pe(4)|pp(4)]:
//     col c: pe at (c>>2)*8+(c&3), pp at (c>>2)*8+4+(c&3)
//     pe = exp((source@W_s)[r][c]);  pp = (source@W_mean)[r][c] + bmean[c]
//  blocks 256..511 (tgt): Et[r][o] = exp((target@W_t)[r][o]+b_s[o]+b_t[o]) f32
// ---------------------------------------------------------------------------
__device__ __forceinline__ f16x8 cvt8(const float* p) {
    f32x4 x = *(const f32x4*)p;
    f32x4 y = *(const f32x4*)(p + 4);
    f16x8 h;
    h[0] = (_Float16)x[0]; h[1] = (_Float16)x[1]; h[2] = (_Float16)x[2]; h[3] = (_Float16)x[3];
    h[4] = (_Float16)y[0]; h[5] = (_Float16)y[1]; h[6] = (_Float16)y[2]; h[7] = (_Float16)y[3];
    return h;
}

__global__ __launch_bounds__(256, 2)
void gemm_prep(const float* __restrict__ source, const float* __restrict__ target,
               const _Float16* __restrict__ WcT, const _Float16* __restrict__ Wt16,
               const float* __restrict__ bmean, const float* __restrict__ b_s,
               const float* __restrict__ b_t,
               _Float16* __restrict__ Ppe, float* __restrict__ Et) {
    __shared__ _Float16 lds[32768];   // SRC path uses 64 KiB, TGT 32 KiB

    const int tid = threadIdx.x;
    const int w = tid >> 6, l = tid & 63;
    const int l15 = l & 15, lq = l >> 4;
    const int b = blockIdx.x;

    if (b < 256) {
        // ---------------- SRC path ----------------
        const int rb = b * 64;
        const float* arow = source + (size_t)(rb + w * 16 + l15) * 256;
        f16x8 af[8];
        #pragma unroll
        for (int s = 0; s < 8; ++s) af[s] = cvt8(arow + s * 32 + lq * 8);

        #pragma unroll
        for (int i = 0; i < 16; ++i) {
            int c = i * 256 + tid;                   // 4096 chunks
            int fi = c >> 6, lane = c & 63;
            int nt = fi >> 3, s = fi & 7;
            f16x8 v = *(const f16x8*)(WcT + (nt * 16 + (lane & 15)) * 256 + s * 32 + (lane >> 4) * 8);
            *(f16x8*)((char*)lds + c * 16) = v;
        }
        __syncthreads();

        const char* bb = (const char*)lds + l * 16;
        f32x4 acc[8] = {};
        #pragma unroll
        for (int s = 0; s < 8; ++s) {
            #pragma unroll
            for (int nt = 0; nt < 8; ++nt) {
                f16x8 bf = *(const f16x8*)(bb + nt * 8192 + s * 1024);
                acc[nt] = __builtin_amdgcn_mfma_f32_16x16x32_f16(af[s], bf, acc[nt], 0, 0, 0);
            }
        }

        float bmv[4];
        #pragma unroll
        for (int nt = 0; nt < 4; ++nt) bmv[nt] = bmean[nt * 16 + l15];
        // interleaved position for col c = nt*16 + l15:
        //   pe: nt*32 + (l15>>2)*8 + (l15&3);  pp: +4
        const int ip = (l15 >> 2) * 8 + (l15 & 3);
        #pragma unroll
        for (int j = 0; j < 4; ++j) {
            int row = rb + w * 16 + lq * 4 + j;
            #pragma unroll
            for (int nt = 0; nt < 4; ++nt) {
                Ppe[row * 128 + nt * 32 + ip]     = (_Float16)__expf(acc[nt][j]);
                Ppe[row * 128 + nt * 32 + ip + 4] = (_Float16)(acc[nt + 4][j] + bmv[nt]);
            }
        }
    } else {
        // ---------------- TGT path ----------------
        const int rb = (b - 256) * 64;
        const float* arow = target + (size_t)(rb + w * 16 + l15) * 256;
        f16x8 af[8];
        #pragma unroll
        for (int s = 0; s < 8; ++s) af[s] = cvt8(arow + s * 32 + lq * 8);

        #pragma unroll
        for (int i = 0; i < 8; ++i) {
            int c = i * 256 + tid;                   // 2048 chunks
            int fi = c >> 6, lane = c & 63;
            int nt = fi >> 3, s = fi & 7;
            f16x8 v = *(const f16x8*)(Wt16 + (nt * 16 + (lane & 15)) * 256 + s * 32 + (lane >> 4) * 8);
            *(f16x8*)((char*)lds + c * 16) = v;
        }
        __syncthreads();

        const char* bb = (const char*)lds + l * 16;
        f32x4 acc[4] = {};
        #pragma unroll
        for (int s = 0; s < 8; ++s) {
            #pragma unroll
            for (int nt = 0; nt < 4; ++nt) {
                f16x8 bf = *(const f16x8*)(bb + nt * 8192 + s * 1024);
                acc[nt] = __builtin_amdgcn_mfma_f32_16x16x32_f16(af[s], bf, acc[nt], 0, 0, 0);
            }
        }

        float bsv[4];
        #pragma unroll
        for (int nt = 0; nt < 4; ++nt) {
            int col = nt * 16 + l15;
            bsv[nt] = b_s[col] + b_t[col];
        }
        #pragma unroll
        for (int j = 0; j < 4; ++j) {
            int row = rb + w * 16 + lq * 4 + j;
            #pragma unroll
            for (int nt = 0; nt < 4; ++nt)
                Et[row * 64 + nt * 16 + l15] = __expf(acc[nt][j] + bsv[nt]);
        }
    }
}

// ---------------------------------------------------------------------------
// epilogue: 2048 blocks x 256 threads; TWO target nodes per wave.
// Row map r = n*32 + lq*8 + g (g=0..7): per-lane CONSECUTIVE neighbor
// indices -> nb loaded as int4 x2 per node. One f16x8 gather per neighbor
// (interleaved [pe4|pp4] layout), all issued up front.
// THIS ROUND'S SINGLE CHANGE: output stores are NONTEMPORAL so the 134 MB
// write stream does not allocate in L2 and evict the Ppe/Et gather tables.
// out[r][o] = pe[nb][o]*Et[n][o] / sum_o(pe*Et) * pp[nb][o]
// ---------------------------------------------------------------------------
__global__ __launch_bounds__(256, 5)
void epilogue(const int* __restrict__ neighbors, const _Float16* __restrict__ Ppe,
              const float* __restrict__ Et, float* __restrict__ out) {
    const int tid = threadIdx.x;
    const int w = tid >> 6, l = tid & 63;
    const int lq = l >> 4, l15 = l & 15;
    const int n0 = blockIdx.x * 8 + w * 2;      // this wave: n0, n0+1
    const int co = l15 * 4;
    const int ro = l15 * 8;                     // elem offset of col-group

    i32x4 na0 = *(const i32x4*)(neighbors + n0 * 32 + lq * 8);
    i32x4 na1 = *(const i32x4*)(neighbors + n0 * 32 + lq * 8 + 4);
    i32x4 nc0 = *(const i32x4*)(neighbors + (n0 + 1) * 32 + lq * 8);
    i32x4 nc1 = *(const i32x4*)(neighbors + (n0 + 1) * 32 + lq * 8 + 4);

    f32x4 et0 = *(const f32x4*)(Et + n0 * 64 + co);
    f32x4 et1 = *(const f32x4*)(Et + (n0 + 1) * 64 + co);

    f16x8 q0[8], q1[8];
    #pragma unroll
    for (int g = 0; g < 4; ++g) q0[g]     = *(const f16x8*)(Ppe + na0[g] * 128 + ro);
    #pragma unroll
    for (int g = 0; g < 4; ++g) q0[4 + g] = *(const f16x8*)(Ppe + na1[g] * 128 + ro);
    #pragma unroll
    for (int g = 0; g < 4; ++g) q1[g]     = *(const f16x8*)(Ppe + nc0[g] * 128 + ro);
    #pragma unroll
    for (int g = 0; g < 4; ++g) q1[4 + g] = *(const f16x8*)(Ppe + nc1[g] * 128 + ro);

    #pragma unroll
    for (int g = 0; g < 8; ++g) {
        float w0 = (float)q0[g][0] * et0[0];
        float w1 = (float)q0[g][1] * et0[1];
        float w2 = (float)q0[g][2] * et0[2];
        float w3 = (float)q0[g][3] * et0[3];
        float s = (w0 + w1) + (w2 + w3);
        s += __shfl_xor(s, 1);
        s += __shfl_xor(s, 2);
        s += __shfl_xor(s, 4);
        s += __shfl_xor(s, 8);
        float inv = 1.0f / s;
        f32x4 o;
        o[0] = w0 * inv * (float)q0[g][4];
        o[1] = w1 * inv * (float)q0[g][5];
        o[2] = w2 * inv * (float)q0[g][6];
        o[3] = w3 * inv * (float)q0[g][7];
        __builtin_nontemporal_store(o, (f32x4*)(out + (size_t)(n0 * 32 + lq * 8 + g) * 64 + co));
    }
    #pragma unroll
    for (int g = 0; g < 8; ++g) {
        float w0 = (float)q1[g][0] * et1[0];
        float w1 = (float)q1[g][1] * et1[1];
        float w2 = (float)q1[g][2] * et1[2];
        float w3 = (float)q1[g][3] * et1[3];
        float s = (w0 + w1) + (w2 + w3);
        s += __shfl_xor(s, 1);
        s += __shfl_xor(s, 2);
        s += __shfl_xor(s, 4);
        s += __shfl_xor(s, 8);
        float inv = 1.0f / s;
        f32x4 o;
        o[0] = w0 * inv * (float)q1[g][4];
        o[1] = w1 * inv * (float)q1[g][5];
        o[2] = w2 * inv * (float)q1[g][6];
        o[3] = w3 * inv * (float)q1[g][7];
        __builtin_nontemporal_store(o, (f32x4*)(out + (size_t)((n0 + 1) * 32 + lq * 8 + g) * 64 + co));
    }
}

// ---------------------------------------------------------------------------
extern "C" void kernel_launch(void* const* d_in, const int* in_sizes, int n_in,
                              void* d_out, int out_size, void* d_ws, size_t ws_size,
                              hipStream_t stream) {
    const float* source    = (const float*)d_in[0];
    const float* target    = (const float*)d_in[1];
    const int*   neighbors = (const int*)d_in[2];
    const float* W_lin     = (const float*)d_in[3];
    const float* b_lin     = (const float*)d_in[4];
    const float* W_s       = (const float*)d_in[5];
    const float* b_s       = (const float*)d_in[6];
    const float* W_t       = (const float*)d_in[7];
    const float* b_t       = (const float*)d_in[8];

    char* ws = (char*)d_ws;
    _Float16* Ppe   = (_Float16*)ws;                          // 4 MiB
    float*    Et    = (float*)(ws + (4u << 20));              // 4 MiB
    _Float16* WcT   = (_Float16*)(ws + (8u << 20));           // 64 KiB
    _Float16* Wt16  = (_Float16*)(ws + (8u << 20) + 65536);   // 32 KiB
    float*    bmean = (float*)(ws + (8u << 20) + 98304);      // 256 B
    float*    out   = (float*)d_out;

    prep_weights<<<128, 256, 0, stream>>>(W_lin, b_lin, W_s, W_t, WcT, Wt16, bmean);
    gemm_prep<<<512, 256, 0, stream>>>(source, target, WcT, Wt16, bmean, b_s, b_t,
                                       Ppe, Et);
    epilogue<<<2048, 256, 0, stream>>>(neighbors, Ppe, Et, out);
}